// Round 1
// baseline (116.524 us; speedup 1.0000x reference)
//
#include <hip/hip_runtime.h>
#include <math.h>

// Problem constants (from reference setup_inputs)
constexpr int N_ = 16;
constexpr int K_ = 32768;
constexpr int C_ = 16;
constexpr int M_ = 128;

constexpr int KC = 512;              // k's staged per pass
constexpr int CPB = 2;               // chunks (passes) per block  (R15)
constexpr int CPW = K_ / (KC * CPB); // 32 blocks per n -> 512 blocks, 2/CU
constexpr int WAVES = 8;             // waves per block (512 threads)

// ws poison: harness re-poisons d_ws to 0xAA before every launch. cnt
// counters start at (int)0xAAAAAAAA (accept 0 base as fallback). rowwin
// slots are written unconditionally by every block before its release, so
// poison is never read there (R15: no atomicMin-vs-poison dependency left).
#define POISON_U 0xAAAAAAAAu

// Agent-scope accessors: coherence-point loads/stores, NO cache-wide wb/inv
// (R3 lesson: all-thread __threadfence() cost 3x).
__device__ __forceinline__ unsigned long long load_agent_u64(
    const unsigned long long* p) {
  return __hip_atomic_load(p, __ATOMIC_RELAXED, __HIP_MEMORY_SCOPE_AGENT);
}
__device__ __forceinline__ void store_agent_u64(unsigned long long* p,
                                                unsigned long long v) {
  __hip_atomic_store(p, v, __ATOMIC_RELAXED, __HIP_MEMORY_SCOPE_AGENT);
}
__device__ __forceinline__ void store_agent_f32(float* p, float v) {
  __hip_atomic_store(p, v, __ATOMIC_RELAXED, __HIP_MEMORY_SCOPE_AGENT);
}
__device__ __forceinline__ float load_agent_f32(const float* p) {
  return __hip_atomic_load(p, __ATOMIC_RELAXED, __HIP_MEMORY_SCOPE_AGENT);
}

// ---------------------------------------------------------------------------
// R15 = R14 (proven: LDS staging, hoisted a1, 4 rows/lane ILP, packed-int-key
// argmax, absmax 0.0) with the atomic/release term halved+cheapened:
//   * CPB=2: each block runs TWO 512-k chunk passes (identical per-chunk key
//     encoding: 23-bit truncated iou | 9-bit reversed idx; signed v_max_i32
//     ranks (iou desc, k asc), ties -> smallest k == jnp.argmax first-max).
//     The two chunk winners are merged IN-REGISTER at full width via the
//     same (~ord(iou&~511))<<32 | global_k u64 ordering the atomicMin chain
//     used -> bit-identical winner set, no numerics change.
//   * atomicMin u64 RMW -> relaxed agent-scope u64 STORE to a private slot
//     rowwin[n][block][m]. Release = __syncthreads (drains vmcnt(0) per
//     wave) + one relaxed atomicAdd(cnt[n]) — the exact pattern already
//     proven for ws2 -> phase-3 visibility.
// Phase 2 (last block per n): min over CPW=32 slot keys/row -> gather/
// losses, 8-wave block reduce -> ws2[n][8]. Phase 3 (last of 16): scalars.
// ---------------------------------------------------------------------------
__global__ __launch_bounds__(512, 4) void fused_loss_kernel(
    const float* __restrict__ pred_boxes,
    const float* __restrict__ pred_cls,
    const float* __restrict__ target,
    unsigned long long* __restrict__ rowwin,  // [N_][CPW][M_]
    float* __restrict__ ws2,                  // [N_][8]
    int* __restrict__ cnt,                    // [N_+1]
    float* __restrict__ out) {
  __shared__ float4 lds4[KC];
  __shared__ float ldsa1[KC];
  __shared__ int key_s[WAVES][CPB][M_];
  __shared__ float red[WAVES][7];
  __shared__ int s_flag;

  const int bx = blockIdx.x;  // 0..CPW-1
  const int n = blockIdx.y;
  const int tid = threadIdx.x;

  const int wv = tid >> 6;          // wave id 0..7
  const int lane = tid & 63;
  const int rb = lane & 31;         // row base: rows rb + 32*j
  const int half = (lane >> 5) & 1; // k-half within the wave's slice pair
  const int ks = (wv * 2 + half) * 32;       // this lane's 32-k slice
  const int hbase = ((1 - half) << 5) | 31;  // idx6 = hbase - kl (bits 0-5)

  // per-lane target values for 4 rows (tboxes = target[...,1:]) — loaded
  // once, reused across both chunk passes.
  float tx1[4], ty1[4], tx2[4], ty2[4], a2[4];
#pragma unroll
  for (int j = 0; j < 4; ++j) {
    const float* tg = target + ((size_t)(n * M_ + rb + 32 * j)) * 5;
    tx1[j] = tg[1];
    ty1[j] = tg[2];
    tx2[j] = tg[3] + 1.0f;
    ty2[j] = tg[4] + 1.0f;
    a2[j] = (tg[3] - tg[1] + 1.0f) * (tg[4] - tg[2] + 1.0f) + 1e-16f;
  }

  for (int cc = 0; cc < CPB; ++cc) {
    const int k0 = (bx * CPB + cc) * KC;

    // ---- stage chunk: 512 k's, one per thread (ref-exact derived values) --
    {
      const float* p = pred_boxes + ((size_t)(n * K_ + k0 + tid)) * 5;
      const float x = p[0];
      const float y = p[1];
      const float bw = p[2];
      const float bh = p[3];
      const float px2 = bw + x;  // ref: pb[...,2] + pb[...,0]
      const float py2 = bh + y;
      lds4[tid] = make_float4(x, y, px2 + 1.0f, py2 + 1.0f);
      // ref-exact: a1 = (p_x2 - p_x1 + 1) * (p_y2 - p_y1 + 1)
      ldsa1[tid] = (px2 - x + 1.0f) * (py2 - y + 1.0f);
    }
    __syncthreads();

    int best[4];
#pragma unroll
    for (int j = 0; j < 4; ++j) best[j] = (int)0x80000000;

#pragma unroll 8
    for (int kl = 0; kl < 32; ++kl) {
      const float4 v = lds4[ks + kl];   // broadcast ds_read_b128 (4 rows)
      const float a1 = ldsa1[ks + kl];  // broadcast ds_read_b32  (4 rows)
      const unsigned idx6 = (unsigned)(hbase - kl);
#pragma unroll
      for (int j = 0; j < 4; ++j) {  // 4 independent chains
        float ww = fminf(v.z, tx2[j]) - fmaxf(v.x, tx1[j]);
        float hh = fminf(v.w, ty2[j]) - fmaxf(v.y, ty1[j]);
        ww = fmaxf(ww, 0.0f);
        hh = fmaxf(hh, 0.0f);
        const float inter = ww * hh;
        const float iou = inter * __builtin_amdgcn_rcpf((a1 + a2[j]) - inter);
        // iou bits 9-31 | idx6 (bits 6-8 left zero for the wave tag)
        const int key = (int)((__float_as_uint(iou) & 0xFFFFFE00u) | idx6);
        best[j] = best[j] > key ? best[j] : key;  // v_max_i32
      }
    }

    // merge the two k-halves (lane ^ 32) in-register; bit5 tag keeps ranking
    // (iou desc, k asc) exact.
#pragma unroll
    for (int j = 0; j < 4; ++j) {
      const int other = __shfl_xor(best[j], 32, 64);
      best[j] = best[j] > other ? best[j] : other;
    }
    // lanes 0..31 publish 4 rows with (7-wv) in bits 6-8
    if (lane < 32) {
      const unsigned wvf = (unsigned)(7 - wv) << 6;
#pragma unroll
      for (int j = 0; j < 4; ++j) {
        const unsigned u = (unsigned)best[j];
        key_s[wv][cc][rb + 32 * j] = (int)((u & 0xFFFFFE00u) | wvf | (u & 63u));
      }
    }
    __syncthreads();  // key_s[.][cc] visible; lds4/ldsa1 free for restage
  }

  // 8-way wave merge per chunk (pure v_max_i32), exact u64 cross-chunk merge
  // in-register, then ONE relaxed agent store per row per block (no RMW).
  if (tid < M_) {
    unsigned long long bestu = ~0ull;
#pragma unroll
    for (int cc = 0; cc < CPB; ++cc) {
      int mg = key_s[0][cc][tid];
#pragma unroll
      for (int w2 = 1; w2 < WAVES; ++w2) {
        const int v = key_s[w2][cc][tid];
        mg = mg > v ? mg : v;
      }
      const unsigned e = (unsigned)mg & 511u;
      const int gk = (bx * CPB + cc) * KC + (511 - (int)e);  // winner's k
      const unsigned tr = (unsigned)mg & 0xFFFFFE00u;        // trunc iou bits
      const unsigned ord = tr ^ (unsigned)(((int)tr >> 31) | 0x80000000);
      const unsigned long long u =
          ((unsigned long long)(~ord) << 32) | (unsigned)gk;
      bestu = u < bestu ? u : bestu;  // ties -> smaller global k (cc=0 first)
    }
    store_agent_u64(&rowwin[((size_t)n * CPW + bx) * M_ + tid], bestu);
  }

  // Release: barrier drains each wave's vmcnt(0); then one relaxed signal.
  __syncthreads();
  if (tid == 0) {
    const unsigned old = (unsigned)atomicAdd(&cnt[n], 1);
    s_flag = (old == POISON_U + (CPW - 1)) || (old == CPW - 1);
  }
  __syncthreads();
  if (!s_flag) return;

  // ================= Phase 2: last block for this n =================
  {
    const int m = tid & (M_ - 1);
    float acc[7] = {0, 0, 0, 0, 0, 0, 0};
    if (tid < M_) {
      // merge the CPW slot keys (min == global first-max argmax)
      unsigned long long bestk = ~0ull;
#pragma unroll
      for (int g = 0; g < CPW; ++g) {
        const unsigned long long pk =
            load_agent_u64(&rowwin[((size_t)n * CPW + g) * M_ + m]);
        bestk = pk < bestk ? pk : bestk;
      }
      const int bidx0 = (int)(unsigned)bestk;  // low 32 bits = winning k

      const float* tg2 = target + ((size_t)(n * M_ + m)) * 5;
      const float t0 = tg2[0], t1 = tg2[1], t2 = tg2[2], t3 = tg2[3],
                  t4 = tg2[4];
      const float sum5 = t0 + t1 + t2 + t3 + t4;
      const float mk = (sum5 != 0.0f) ? 1.0f : 0.0f;
      const int bidx = (sum5 != 0.0f) ? bidx0 : 0;

      const float* pb = pred_boxes + ((size_t)(n * K_ + bidx)) * 5;
      const float b0 = pb[0], b1 = pb[1], bw = pb[2], bh = pb[3];

      // cross-entropy via log-softmax over C=16
      const float4* pc =
          (const float4*)(pred_cls + ((size_t)(n * K_ + bidx)) * C_);
      float vals[C_];
#pragma unroll
      for (int q = 0; q < 4; ++q) {
        const float4 vv = pc[q];
        vals[q * 4 + 0] = vv.x;
        vals[q * 4 + 1] = vv.y;
        vals[q * 4 + 2] = vv.z;
        vals[q * 4 + 3] = vv.w;
      }
      int tcls = (int)t0;
      tcls = tcls < 0 ? 0 : (tcls >= C_ ? C_ - 1 : tcls);
      float mx = -INFINITY;
#pragma unroll
      for (int q = 0; q < C_; ++q) mx = fmaxf(mx, vals[q]);
      float se = 0.0f;
#pragma unroll
      for (int q = 0; q < C_; ++q) se += expf(vals[q] - mx);
      const float ce2 = logf(se) + mx - vals[tcls];

      const float dx = b0 - t1;
      const float dy = b1 - t2;
      const float dw = bw - (t3 - t1);
      const float dh = bh - (t4 - t2);

      // conf: conf_idx==0 => sigmoid(pred_boxes[n,0,4]) for every m
      const float pcf = pred_boxes[(size_t)n * K_ * 5 + 4];
      const float bc = 1.0f / (1.0f + expf(-pcf));
      const float bce = (bc > 0.5f) ? -logf(bc) : -logf(1.0f - bc);

      acc[0] = mk;
      acc[1] = mk * ce2;
      acc[2] = mk * dx * dx;
      acc[3] = mk * dy * dy;
      acc[4] = mk * dw * dw;
      acc[5] = mk * dh * dh;
      acc[6] = mk * bce;
    }

    // block reduce: 8 waves shuffle-reduce, LDS combine
#pragma unroll
    for (int i = 0; i < 7; ++i) {
      float v = acc[i];
      for (int off = 32; off > 0; off >>= 1) v += __shfl_down(v, off, 64);
      acc[i] = v;
    }
    const int lane2 = tid & 63;
    const int wid = tid >> 6;
    if (lane2 == 0) {
#pragma unroll
      for (int i = 0; i < 7; ++i) red[wid][i] = acc[i];
    }
    __syncthreads();

    if (tid == 0) {
      float sum7[7];
#pragma unroll
      for (int i = 0; i < 7; ++i) {
        float s = 0.0f;
#pragma unroll
        for (int w2 = 0; w2 < WAVES; ++w2) s += red[w2][i];
        sum7[i] = s;
      }
#pragma unroll
      for (int i = 0; i < 7; ++i) store_agent_f32(&ws2[n * 8 + i], sum7[i]);
    }
    __syncthreads();  // release: drains tid0's stores before the signal
    if (tid == 0) {
      const unsigned old2 = (unsigned)atomicAdd(&cnt[N_], 1);
      s_flag = (old2 == POISON_U + (N_ - 1)) || (old2 == N_ - 1);
    }
    __syncthreads();
  }

  // ================= Phase 3: global finalizer =================
  if (s_flag && tid == 0) {
    float s[7] = {0, 0, 0, 0, 0, 0, 0};
    for (int nn = 0; nn < N_; ++nn)
#pragma unroll
      for (int i = 0; i < 7; ++i) s[i] += load_agent_f32(&ws2[nn * 8 + i]);
    const float denom = s[0];
    const float lc = s[1] / denom;
    const float lx = s[2] / denom;
    const float ly = s[3] / denom;
    const float lw = s[4] / denom;
    const float lh = s[5] / denom;
    const float lf = s[6] / denom;
    out[0] = lc + lx + ly + lw + lh + lf;
    out[1] = lc;
    out[2] = lx;
    out[3] = ly;
    out[4] = lw;
    out[5] = lh;
    out[6] = lf;
  }
}

extern "C" void kernel_launch(void* const* d_in, const int* in_sizes, int n_in,
                              void* d_out, int out_size, void* d_ws, size_t ws_size,
                              hipStream_t stream) {
  const float* pred_boxes = (const float*)d_in[0];
  const float* pred_cls = (const float*)d_in[1];
  const float* target = (const float*)d_in[2];
  float* out = (float*)d_out;

  // workspace layout
  unsigned long long* rowwin = (unsigned long long*)d_ws;  // 16*32*128 u64
  float* ws2 = (float*)(rowwin + (size_t)N_ * CPW * M_);   // 16*8 floats
  int* cnt = (int*)(ws2 + N_ * 8);                         // 17 ints (0xAA)

  dim3 g(CPW, N_);
  fused_loss_kernel<<<g, 512, 0, stream>>>(pred_boxes, pred_cls, target,
                                           rowwin, ws2, cnt, out);
}

// Round 2
// 112.649 us; speedup vs baseline: 1.0344x; 1.0344x over previous
//
#include <hip/hip_runtime.h>
#include <math.h>

// Problem constants (from reference setup_inputs)
constexpr int N_ = 16;
constexpr int K_ = 32768;
constexpr int C_ = 16;
constexpr int M_ = 128;

constexpr int KC = 512;              // k's staged per pass
constexpr int CPB = 2;               // chunks (passes) per block
constexpr int CPW = K_ / (KC * CPB); // 32 blocks per n -> 512 blocks, 2/CU
constexpr int WAVES = 8;             // waves per block (512 threads)

// ws poison: harness re-poisons d_ws to 0xAA before every launch. cnt
// counters start at (int)0xAAAAAAAA (accept 0 base as fallback). rowwin
// slots are written unconditionally by every block before its release, so
// poison is never read there.
#define POISON_U 0xAAAAAAAAu

// Agent-scope accessors: coherence-point loads/stores, NO cache-wide wb/inv
// (R3 lesson: all-thread __threadfence() cost 3x).
__device__ __forceinline__ unsigned long long load_agent_u64(
    const unsigned long long* p) {
  return __hip_atomic_load(p, __ATOMIC_RELAXED, __HIP_MEMORY_SCOPE_AGENT);
}
__device__ __forceinline__ void store_agent_u64(unsigned long long* p,
                                                unsigned long long v) {
  __hip_atomic_store(p, v, __ATOMIC_RELAXED, __HIP_MEMORY_SCOPE_AGENT);
}
__device__ __forceinline__ void store_agent_f32(float* p, float v) {
  __hip_atomic_store(p, v, __ATOMIC_RELAXED, __HIP_MEMORY_SCOPE_AGENT);
}
__device__ __forceinline__ float load_agent_f32(const float* p) {
  return __hip_atomic_load(p, __ATOMIC_RELAXED, __HIP_MEMORY_SCOPE_AGENT);
}

// R16: single-instruction float min/max (bypass IEEE canonicalization that
// hipcc inserts around fminf/fmaxf for memory-sourced operands). Bit-exact
// vs fminf/fmaxf for non-NaN inputs (all data here is finite).
__device__ __forceinline__ float vminf_(float a, float b) {
  float r;
  asm("v_min_f32 %0, %1, %2" : "=v"(r) : "v"(a), "v"(b));
  return r;
}
__device__ __forceinline__ float vmaxf_(float a, float b) {
  float r;
  asm("v_max_f32 %0, %1, %2" : "=v"(r) : "v"(a), "v"(b));
  return r;
}
__device__ __forceinline__ float vmax0_(float a) {  // max(a, 0.0f)
  float r;
  asm("v_max_f32 %0, 0, %1" : "=v"(r) : "v"(a));
  return r;
}
// key = (iou_bits & 0xFFFFFE00) | (idx6 & 0x1FF) in ONE v_bfi_b32.
__device__ __forceinline__ int vbfi_key_(unsigned mask, unsigned iou_bits,
                                         unsigned idx6) {
  int r;
  asm("v_bfi_b32 %0, %1, %2, %3" : "=v"(r) : "v"(mask), "v"(iou_bits),
      "v"(idx6));
  return r;
}

// ---------------------------------------------------------------------------
// R16 = R15 (proven: LDS staging, hoisted a1, 4 rows/lane ILP, packed-int-key
// argmax, CPB=2 in-register chunk merge, relaxed-store publish, absmax 0.0)
// with the hot loop's 6 min/max + clamp + key-pack re-expressed as single
// VALU instructions (asm v_min/v_max/v_bfi). Numerics are bit-identical:
// canonicalization is the identity for finite floats; bfi computes the exact
// same (iou&~511)|idx6. Target: the measured 2x VALU-instruction inflation
// (27us busy vs 13.6us algorithmic floor at VALUBusy=62%).
// ---------------------------------------------------------------------------
__global__ __launch_bounds__(512, 4) void fused_loss_kernel(
    const float* __restrict__ pred_boxes,
    const float* __restrict__ pred_cls,
    const float* __restrict__ target,
    unsigned long long* __restrict__ rowwin,  // [N_][CPW][M_]
    float* __restrict__ ws2,                  // [N_][8]
    int* __restrict__ cnt,                    // [N_+1]
    float* __restrict__ out) {
  __shared__ float4 lds4[KC];
  __shared__ float ldsa1[KC];
  __shared__ int key_s[WAVES][CPB][M_];
  __shared__ float red[WAVES][7];
  __shared__ int s_flag;

  const int bx = blockIdx.x;  // 0..CPW-1
  const int n = blockIdx.y;
  const int tid = threadIdx.x;

  const int wv = tid >> 6;          // wave id 0..7
  const int lane = tid & 63;
  const int rb = lane & 31;         // row base: rows rb + 32*j
  const int half = (lane >> 5) & 1; // k-half within the wave's slice pair
  const int ks = (wv * 2 + half) * 32;       // this lane's 32-k slice
  const int hbase = ((1 - half) << 5) | 31;  // idx6 = hbase - kl (bits 0-5)

  // per-lane target values for 4 rows (tboxes = target[...,1:]) — loaded
  // once, reused across both chunk passes.
  float tx1[4], ty1[4], tx2[4], ty2[4], a2[4];
#pragma unroll
  for (int j = 0; j < 4; ++j) {
    const float* tg = target + ((size_t)(n * M_ + rb + 32 * j)) * 5;
    tx1[j] = tg[1];
    ty1[j] = tg[2];
    tx2[j] = tg[3] + 1.0f;
    ty2[j] = tg[4] + 1.0f;
    a2[j] = (tg[3] - tg[1] + 1.0f) * (tg[4] - tg[2] + 1.0f) + 1e-16f;
  }

  const unsigned keymask = 0xFFFFFE00u;  // hoisted into a VGPR once

  for (int cc = 0; cc < CPB; ++cc) {
    const int k0 = (bx * CPB + cc) * KC;

    // ---- stage chunk: 512 k's, one per thread (ref-exact derived values) --
    {
      const float* p = pred_boxes + ((size_t)(n * K_ + k0 + tid)) * 5;
      const float x = p[0];
      const float y = p[1];
      const float bw = p[2];
      const float bh = p[3];
      const float px2 = bw + x;  // ref: pb[...,2] + pb[...,0]
      const float py2 = bh + y;
      lds4[tid] = make_float4(x, y, px2 + 1.0f, py2 + 1.0f);
      // ref-exact: a1 = (p_x2 - p_x1 + 1) * (p_y2 - p_y1 + 1)
      ldsa1[tid] = (px2 - x + 1.0f) * (py2 - y + 1.0f);
    }
    __syncthreads();

    int best[4];
#pragma unroll
    for (int j = 0; j < 4; ++j) best[j] = (int)0x80000000;

#pragma unroll 8
    for (int kl = 0; kl < 32; ++kl) {
      const float4 v = lds4[ks + kl];   // broadcast ds_read_b128 (4 rows)
      const float a1 = ldsa1[ks + kl];  // broadcast ds_read_b32  (4 rows)
      const unsigned idx6 = (unsigned)(hbase - kl);
#pragma unroll
      for (int j = 0; j < 4; ++j) {  // 4 independent chains
        float ww = vminf_(v.z, tx2[j]) - vmaxf_(v.x, tx1[j]);
        float hh = vminf_(v.w, ty2[j]) - vmaxf_(v.y, ty1[j]);
        ww = vmax0_(ww);
        hh = vmax0_(hh);
        const float inter = ww * hh;
        const float iou = inter * __builtin_amdgcn_rcpf((a1 + a2[j]) - inter);
        // iou bits 9-31 | idx6 (bits 6-8 left zero for the wave tag)
        const int key = vbfi_key_(keymask, __float_as_uint(iou), idx6);
        best[j] = best[j] > key ? best[j] : key;  // v_max_i32
      }
    }

    // merge the two k-halves (lane ^ 32) in-register; bit5 tag keeps ranking
    // (iou desc, k asc) exact.
#pragma unroll
    for (int j = 0; j < 4; ++j) {
      const int other = __shfl_xor(best[j], 32, 64);
      best[j] = best[j] > other ? best[j] : other;
    }
    // lanes 0..31 publish 4 rows with (7-wv) in bits 6-8
    if (lane < 32) {
      const unsigned wvf = (unsigned)(7 - wv) << 6;
#pragma unroll
      for (int j = 0; j < 4; ++j) {
        const unsigned u = (unsigned)best[j];
        key_s[wv][cc][rb + 32 * j] = (int)((u & 0xFFFFFE00u) | wvf | (u & 63u));
      }
    }
    __syncthreads();  // key_s[.][cc] visible; lds4/ldsa1 free for restage
  }

  // 8-way wave merge per chunk (pure v_max_i32), exact u64 cross-chunk merge
  // in-register, then ONE relaxed agent store per row per block (no RMW).
  if (tid < M_) {
    unsigned long long bestu = ~0ull;
#pragma unroll
    for (int cc = 0; cc < CPB; ++cc) {
      int mg = key_s[0][cc][tid];
#pragma unroll
      for (int w2 = 1; w2 < WAVES; ++w2) {
        const int v = key_s[w2][cc][tid];
        mg = mg > v ? mg : v;
      }
      const unsigned e = (unsigned)mg & 511u;
      const int gk = (bx * CPB + cc) * KC + (511 - (int)e);  // winner's k
      const unsigned tr = (unsigned)mg & 0xFFFFFE00u;        // trunc iou bits
      const unsigned ord = tr ^ (unsigned)(((int)tr >> 31) | 0x80000000);
      const unsigned long long u =
          ((unsigned long long)(~ord) << 32) | (unsigned)gk;
      bestu = u < bestu ? u : bestu;  // ties -> smaller global k (cc=0 first)
    }
    store_agent_u64(&rowwin[((size_t)n * CPW + bx) * M_ + tid], bestu);
  }

  // Release: barrier drains each wave's vmcnt(0); then one relaxed signal.
  __syncthreads();
  if (tid == 0) {
    const unsigned old = (unsigned)atomicAdd(&cnt[n], 1);
    s_flag = (old == POISON_U + (CPW - 1)) || (old == CPW - 1);
  }
  __syncthreads();
  if (!s_flag) return;

  // ================= Phase 2: last block for this n =================
  {
    const int m = tid & (M_ - 1);
    float acc[7] = {0, 0, 0, 0, 0, 0, 0};
    if (tid < M_) {
      // merge the CPW slot keys (min == global first-max argmax)
      unsigned long long bestk = ~0ull;
#pragma unroll
      for (int g = 0; g < CPW; ++g) {
        const unsigned long long pk =
            load_agent_u64(&rowwin[((size_t)n * CPW + g) * M_ + m]);
        bestk = pk < bestk ? pk : bestk;
      }
      const int bidx0 = (int)(unsigned)bestk;  // low 32 bits = winning k

      const float* tg2 = target + ((size_t)(n * M_ + m)) * 5;
      const float t0 = tg2[0], t1 = tg2[1], t2 = tg2[2], t3 = tg2[3],
                  t4 = tg2[4];
      const float sum5 = t0 + t1 + t2 + t3 + t4;
      const float mk = (sum5 != 0.0f) ? 1.0f : 0.0f;
      const int bidx = (sum5 != 0.0f) ? bidx0 : 0;

      const float* pb = pred_boxes + ((size_t)(n * K_ + bidx)) * 5;
      const float b0 = pb[0], b1 = pb[1], bw = pb[2], bh = pb[3];

      // cross-entropy via log-softmax over C=16
      const float4* pc =
          (const float4*)(pred_cls + ((size_t)(n * K_ + bidx)) * C_);
      float vals[C_];
#pragma unroll
      for (int q = 0; q < 4; ++q) {
        const float4 vv = pc[q];
        vals[q * 4 + 0] = vv.x;
        vals[q * 4 + 1] = vv.y;
        vals[q * 4 + 2] = vv.z;
        vals[q * 4 + 3] = vv.w;
      }
      int tcls = (int)t0;
      tcls = tcls < 0 ? 0 : (tcls >= C_ ? C_ - 1 : tcls);
      float mx = -INFINITY;
#pragma unroll
      for (int q = 0; q < C_; ++q) mx = fmaxf(mx, vals[q]);
      float se = 0.0f;
#pragma unroll
      for (int q = 0; q < C_; ++q) se += expf(vals[q] - mx);
      const float ce2 = logf(se) + mx - vals[tcls];

      const float dx = b0 - t1;
      const float dy = b1 - t2;
      const float dw = bw - (t3 - t1);
      const float dh = bh - (t4 - t2);

      // conf: conf_idx==0 => sigmoid(pred_boxes[n,0,4]) for every m
      const float pcf = pred_boxes[(size_t)n * K_ * 5 + 4];
      const float bc = 1.0f / (1.0f + expf(-pcf));
      const float bce = (bc > 0.5f) ? -logf(bc) : -logf(1.0f - bc);

      acc[0] = mk;
      acc[1] = mk * ce2;
      acc[2] = mk * dx * dx;
      acc[3] = mk * dy * dy;
      acc[4] = mk * dw * dw;
      acc[5] = mk * dh * dh;
      acc[6] = mk * bce;
    }

    // block reduce: 8 waves shuffle-reduce, LDS combine
#pragma unroll
    for (int i = 0; i < 7; ++i) {
      float v = acc[i];
      for (int off = 32; off > 0; off >>= 1) v += __shfl_down(v, off, 64);
      acc[i] = v;
    }
    const int lane2 = tid & 63;
    const int wid = tid >> 6;
    if (lane2 == 0) {
#pragma unroll
      for (int i = 0; i < 7; ++i) red[wid][i] = acc[i];
    }
    __syncthreads();

    if (tid == 0) {
      float sum7[7];
#pragma unroll
      for (int i = 0; i < 7; ++i) {
        float s = 0.0f;
#pragma unroll
        for (int w2 = 0; w2 < WAVES; ++w2) s += red[w2][i];
        sum7[i] = s;
      }
#pragma unroll
      for (int i = 0; i < 7; ++i) store_agent_f32(&ws2[n * 8 + i], sum7[i]);
    }
    __syncthreads();  // release: drains tid0's stores before the signal
    if (tid == 0) {
      const unsigned old2 = (unsigned)atomicAdd(&cnt[N_], 1);
      s_flag = (old2 == POISON_U + (N_ - 1)) || (old2 == N_ - 1);
    }
    __syncthreads();
  }

  // ================= Phase 3: global finalizer =================
  if (s_flag && tid == 0) {
    float s[7] = {0, 0, 0, 0, 0, 0, 0};
    for (int nn = 0; nn < N_; ++nn)
#pragma unroll
      for (int i = 0; i < 7; ++i) s[i] += load_agent_f32(&ws2[nn * 8 + i]);
    const float denom = s[0];
    const float lc = s[1] / denom;
    const float lx = s[2] / denom;
    const float ly = s[3] / denom;
    const float lw = s[4] / denom;
    const float lh = s[5] / denom;
    const float lf = s[6] / denom;
    out[0] = lc + lx + ly + lw + lh + lf;
    out[1] = lc;
    out[2] = lx;
    out[3] = ly;
    out[4] = lw;
    out[5] = lh;
    out[6] = lf;
  }
}

extern "C" void kernel_launch(void* const* d_in, const int* in_sizes, int n_in,
                              void* d_out, int out_size, void* d_ws, size_t ws_size,
                              hipStream_t stream) {
  const float* pred_boxes = (const float*)d_in[0];
  const float* pred_cls = (const float*)d_in[1];
  const float* target = (const float*)d_in[2];
  float* out = (float*)d_out;

  // workspace layout
  unsigned long long* rowwin = (unsigned long long*)d_ws;  // 16*32*128 u64
  float* ws2 = (float*)(rowwin + (size_t)N_ * CPW * M_);   // 16*8 floats
  int* cnt = (int*)(ws2 + N_ * 8);                         // 17 ints (0xAA)

  dim3 g(CPW, N_);
  fused_loss_kernel<<<g, 512, 0, stream>>>(pred_boxes, pred_cls, target,
                                           rowwin, ws2, cnt, out);
}